// Round 1
// baseline (607.151 us; speedup 1.0000x reference)
//
#include <hip/hip_runtime.h>
#include <math.h>

#define BATCH 64
#define APB 512
#define NA 6
#define NG 5832  // 18^3

__device__ __forceinline__ float leaky(float v){ return v >= 0.f ? v : 0.01f*v; }

// ---------------- blur: one workgroup per (batch, atom_type) segment ----------------
__global__ __launch_bounds__(256) void blur_kernel(const float* __restrict__ x,
                                                   float* __restrict__ fields)
{
  const int seg   = blockIdx.x;          // 0..383
  const int batch = seg / NA;
  const int t     = seg - batch * NA;
  const int tid   = threadIdx.x;

  __shared__ float acc[NG];
  __shared__ float red[4];

  #pragma unroll
  for (int i = 0; i < 23; i++){ int m = tid + i*256; if (m < NG) acc[m] = 0.f; }

  // precompute grid coords for this thread's cells (m = tid + i*256)
  float gx[23], gy[23], gz[23];
  #pragma unroll
  for (int i = 0; i < 23; i++){
    int m  = tid + i*256;
    int ix = m / 324; int rem = m - ix*324;
    int iy = rem / 18; int iz = rem - iy*18;
    gx[i] = (float)ix - 8.5f;
    gy[i] = (float)iy - 8.5f;
    gz[i] = (float)iz - 8.5f;
  }
  const bool v22 = (tid + 22*256) < NG;
  __syncthreads();

  const float* xb = x + (size_t)batch * APB * 5;
  for (int j = 0; j < APB; j++){
    const float* row = xb + j*5;
    if ((int)row[1] != t) continue;     // uniform branch (same row for whole block)
    float px = row[2], py = row[3], pz = row[4];

    float v[23];
    float ps = 0.f;
    #pragma unroll
    for (int i = 0; i < 23; i++){
      float dx = px - gx[i], dy = py - gy[i], dz = pz - gz[i];
      float d2 = dx*dx + dy*dy + dz*dz;
      float e  = __expf(d2 * (-1.0f/0.72f));   // SIGP2 = 0.72
      if (i == 22 && !v22) e = 0.f;
      v[i] = e; ps += e;
    }
    // block reduction of ps
    #pragma unroll
    for (int d = 32; d > 0; d >>= 1) ps += __shfl_down(ps, d);
    int lane = tid & 63, wid = tid >> 6;
    if (lane == 0) red[wid] = ps;
    __syncthreads();
    float tot = red[0] + red[1] + red[2] + red[3];
    __syncthreads();
    float inv = 1.f / (tot + 1e-6f);
    #pragma unroll
    for (int i = 0; i < 23; i++){
      int m = tid + i*256;
      if (i < 22 || v22) acc[m] += v[i] * inv;
    }
  }
  __syncthreads();
  float* fo = fields + (size_t)seg * NG;
  #pragma unroll
  for (int i = 0; i < 23; i++){ int m = tid + i*256; if (m < NG) fo[m] = acc[m]; }
}

// ---------------- fused conv3x3x3 (SAME) + bias + maxpool 2x2x2 ----------------
template<int IC, int OC, int S, int P>
__global__ __launch_bounds__(256) void convpool_kernel(const float* __restrict__ in,
                                                       const float* __restrict__ w,
                                                       const float* __restrict__ bias,
                                                       float* __restrict__ out)
{
  int o = blockIdx.x*256 + threadIdx.x;
  constexpr int TOT = BATCH*OC*P*P*P;
  if (o >= TOT) return;
  int px = o % P; int t1 = o / P;
  int py = t1 % P; t1 /= P;
  int pz = t1 % P; t1 /= P;
  int oc = t1 % OC; int b = t1 / OC;

  float bb = bias[oc];
  float acc[8];
  #pragma unroll
  for (int i = 0; i < 8; i++) acc[i] = 0.f;

  const int z0 = 2*pz - 1, y0 = 2*py - 1, x0 = 2*px - 1;
  for (int ic = 0; ic < IC; ic++){
    const float* ip = in + (size_t)(b*IC + ic) * S*S*S;
    float r[64];
    #pragma unroll
    for (int dz = 0; dz < 4; dz++){
      int z = z0 + dz; bool zok = (unsigned)z < (unsigned)S;
      #pragma unroll
      for (int dy = 0; dy < 4; dy++){
        int y = y0 + dy; bool yok = zok && ((unsigned)y < (unsigned)S);
        #pragma unroll
        for (int dx = 0; dx < 4; dx++){
          int xx = x0 + dx; bool ok = yok && ((unsigned)xx < (unsigned)S);
          r[(dz*4+dy)*4+dx] = ok ? ip[(z*S + y)*S + xx] : 0.f;
        }
      }
    }
    const float* wp = w + (size_t)(oc*IC + ic) * 27;
    float wr[27];
    #pragma unroll
    for (int k = 0; k < 27; k++) wr[k] = wp[k];
    #pragma unroll
    for (int sz = 0; sz < 2; sz++)
      #pragma unroll
      for (int sy = 0; sy < 2; sy++)
        #pragma unroll
        for (int sx = 0; sx < 2; sx++){
          float a = acc[(sz*2+sy)*2+sx];
          #pragma unroll
          for (int dz = 0; dz < 3; dz++)
            #pragma unroll
            for (int dy = 0; dy < 3; dy++)
              #pragma unroll
              for (int dx = 0; dx < 3; dx++)
                a = fmaf(r[((sz+dz)*4 + (sy+dy))*4 + (sx+dx)], wr[(dz*3+dy)*3+dx], a);
          acc[(sz*2+sy)*2+sx] = a;
        }
  }
  float m = acc[0] + bb;
  #pragma unroll
  for (int i = 1; i < 8; i++) m = fmaxf(m, acc[i] + bb);
  out[o] = m;
}

// ---------------- per-channel BN stats over (N, spatial) ----------------
template<int C, int S3>
__global__ __launch_bounds__(256) void bnstats_kernel(const float* __restrict__ v,
                                                      float* __restrict__ mean,
                                                      float* __restrict__ istd)
{
  int c = blockIdx.x;
  float s = 0.f, s2 = 0.f;
  for (int idx = threadIdx.x; idx < BATCH*S3; idx += 256){
    int b = idx / S3; int sp = idx - b*S3;
    float xv = v[(size_t)(b*C + c)*S3 + sp];
    s += xv; s2 += xv*xv;
  }
  #pragma unroll
  for (int d = 32; d > 0; d >>= 1){ s += __shfl_down(s, d); s2 += __shfl_down(s2, d); }
  __shared__ float rs[4], rq[4];
  int lane = threadIdx.x & 63, wid = threadIdx.x >> 6;
  if (lane == 0){ rs[wid] = s; rq[wid] = s2; }
  __syncthreads();
  if (threadIdx.x == 0){
    float ts = rs[0]+rs[1]+rs[2]+rs[3];
    float tq = rq[0]+rq[1]+rq[2]+rq[3];
    float n  = (float)(BATCH*S3);
    float m  = ts / n;
    float var = tq / n - m*m;
    mean[c] = m; istd[c] = rsqrtf(var + 1e-5f);
  }
}

// ---------------- BN apply + leaky ----------------
template<int C, int S3>
__global__ __launch_bounds__(256) void bnapply_kernel(float* __restrict__ v,
                                                      const float* __restrict__ mean,
                                                      const float* __restrict__ istd,
                                                      const float* __restrict__ g,
                                                      const float* __restrict__ bb)
{
  int i = blockIdx.x*256 + threadIdx.x;
  if (i >= BATCH*C*S3) return;
  int c = (i / S3) % C;
  float xv = v[i];
  xv = (xv - mean[c]) * istd[c] * g[c] + bb[c];
  v[i] = leaky(xv);
}

// ---------------- fully connected: Y[64,O] = X[64,I] @ W[O,I]^T + b ----------------
template<int I, int O>
__global__ __launch_bounds__(256) void fc_kernel(const float* __restrict__ X,
                                                 const float* __restrict__ W,
                                                 const float* __restrict__ bias,
                                                 float* __restrict__ Y)
{
  int o = blockIdx.x*256 + threadIdx.x;
  if (o >= BATCH*O) return;
  int f = o % O; int r = o / O;
  const float4* xr = (const float4*)(X + (size_t)r*I);
  const float4* wr = (const float4*)(W + (size_t)f*I);
  float a = 0.f;
  #pragma unroll 4
  for (int i = 0; i < I/4; i++){
    float4 xv = xr[i], wv = wr[i];
    a = fmaf(xv.x, wv.x, a); a = fmaf(xv.y, wv.y, a);
    a = fmaf(xv.z, wv.z, a); a = fmaf(xv.w, wv.w, a);
  }
  Y[o] = a + bias[f];
}

// ---------------- train-mode BN over batch (=64 = one wave per feature) + leaky ----------------
template<int O>
__global__ __launch_bounds__(256) void bnrow_kernel(float* __restrict__ Y,
                                                    const float* __restrict__ g,
                                                    const float* __restrict__ bb)
{
  int gt = blockIdx.x*256 + threadIdx.x;
  int f = gt >> 6;       // one wave per feature
  int lane = gt & 63;    // lane = batch row
  if (f >= O) return;
  float xv = Y[(size_t)lane*O + f];
  float s = xv, s2 = xv*xv;
  #pragma unroll
  for (int d = 32; d > 0; d >>= 1){ s += __shfl_down(s, d); s2 += __shfl_down(s2, d); }
  s = __shfl(s, 0); s2 = __shfl(s2, 0);
  float m   = s * (1.f/64.f);
  float var = s2 * (1.f/64.f) - m*m;
  float is  = rsqrtf(var + 1e-5f);
  float y = (xv - m) * is * g[f] + bb[f];
  Y[(size_t)lane*O + f] = leaky(y);
}

// ---------------- fc2(256->100)+leaky fused with head(100->20) ----------------
__global__ __launch_bounds__(128) void mlp_tail_kernel(const float* __restrict__ H,
                                                       const float* __restrict__ w2,
                                                       const float* __restrict__ b2,
                                                       const float* __restrict__ hw,
                                                       const float* __restrict__ hb,
                                                       float* __restrict__ out)
{
  int b = blockIdx.x;
  __shared__ float y2[100];
  const float4* xr = (const float4*)(H + (size_t)b*256);
  for (int f = threadIdx.x; f < 100; f += 128){
    const float4* wr = (const float4*)(w2 + (size_t)f*256);
    float a = 0.f;
    #pragma unroll 4
    for (int i = 0; i < 64; i++){
      float4 xv = xr[i], wv = wr[i];
      a = fmaf(xv.x, wv.x, a); a = fmaf(xv.y, wv.y, a);
      a = fmaf(xv.z, wv.z, a); a = fmaf(xv.w, wv.w, a);
    }
    y2[f] = leaky(a + b2[f]);
  }
  __syncthreads();
  for (int oo = threadIdx.x; oo < 20; oo += 128){
    float a = hb[oo];
    for (int i = 0; i < 100; i++) a = fmaf(y2[i], hw[oo*100 + i], a);
    out[b*20 + oo] = a;
  }
}

extern "C" void kernel_launch(void* const* d_in, const int* in_sizes, int n_in,
                              void* d_out, int out_size, void* d_ws, size_t ws_size,
                              hipStream_t stream)
{
  const float* x   = (const float*)d_in[0];
  const float* cw0 = (const float*)d_in[2];  const float* cb0 = (const float*)d_in[3];
  const float* g0  = (const float*)d_in[4];  const float* bb0 = (const float*)d_in[5];
  const float* cw1 = (const float*)d_in[6];  const float* cb1 = (const float*)d_in[7];
  const float* g1  = (const float*)d_in[8];  const float* bb1 = (const float*)d_in[9];
  const float* cw2 = (const float*)d_in[10]; const float* cb2 = (const float*)d_in[11];
  const float* g2  = (const float*)d_in[12]; const float* bb2 = (const float*)d_in[13];
  const float* mw0 = (const float*)d_in[14]; const float* mb0 = (const float*)d_in[15];
  const float* g3  = (const float*)d_in[16]; const float* bb3 = (const float*)d_in[17];
  const float* mw1 = (const float*)d_in[18]; const float* mb1 = (const float*)d_in[19];
  const float* g4  = (const float*)d_in[20]; const float* bb4 = (const float*)d_in[21];
  const float* mw2 = (const float*)d_in[22]; const float* mb2 = (const float*)d_in[23];
  const float* hw  = (const float*)d_in[24]; const float* hb  = (const float*)d_in[25];

  float* ws     = (float*)d_ws;
  float* fields = ws;                    // 64*6*5832   = 2239488
  float* p0     = fields + 2239488;      // 64*16*729   = 746496
  float* p1     = p0 + 746496;           // 64*32*64    = 131072
  float* p2     = p1 + 131072;           // 64*64*8     = 32768 (== flattened MLP input)
  float* y0     = p2 + 32768;            // 64*512
  float* y1     = y0 + 32768;            // 64*256
  float* mean   = y1 + 16384;            // 64
  float* istd   = mean + 64;             // 64
  float* outp   = (float*)d_out;

  blur_kernel<<<384, 256, 0, stream>>>(x, fields);

  convpool_kernel<6,16,18,9><<<(746496+255)/256, 256, 0, stream>>>(fields, cw0, cb0, p0);
  bnstats_kernel<16,729><<<16, 256, 0, stream>>>(p0, mean, istd);
  bnapply_kernel<16,729><<<(746496+255)/256, 256, 0, stream>>>(p0, mean, istd, g0, bb0);

  convpool_kernel<16,32,9,4><<<(131072+255)/256, 256, 0, stream>>>(p0, cw1, cb1, p1);
  bnstats_kernel<32,64><<<32, 256, 0, stream>>>(p1, mean, istd);
  bnapply_kernel<32,64><<<512, 256, 0, stream>>>(p1, mean, istd, g1, bb1);

  convpool_kernel<32,64,4,2><<<128, 256, 0, stream>>>(p1, cw2, cb2, p2);
  bnstats_kernel<64,8><<<64, 256, 0, stream>>>(p2, mean, istd);
  bnapply_kernel<64,8><<<128, 256, 0, stream>>>(p2, mean, istd, g2, bb2);

  fc_kernel<512,512><<<128, 256, 0, stream>>>(p2, mw0, mb0, y0);
  bnrow_kernel<512><<<128, 256, 0, stream>>>(y0, g3, bb3);
  fc_kernel<512,256><<<64, 256, 0, stream>>>(y0, mw1, mb1, y1);
  bnrow_kernel<256><<<64, 256, 0, stream>>>(y1, g4, bb4);
  mlp_tail_kernel<<<64, 128, 0, stream>>>(y1, mw2, mb2, hw, hb, outp);
}

// Round 2
// 462.730 us; speedup vs baseline: 1.3121x; 1.3121x over previous
//
#include <hip/hip_runtime.h>
#include <math.h>

#define BATCH 64
#define APB 512
#define NA 6
#define NG 5832  // 18^3

__device__ __forceinline__ float leaky(float v){ return v >= 0.f ? v : 0.01f*v; }

// ============ blur phase 1: per-atom separable 1-D Gaussian tables ============
// tab[a][0:18]  = exp(-(px-g)^2/S) * inv_norm   (inv folded into x-axis)
// tab[a][18:36] = exp(-(py-g)^2/S)
// tab[a][36:54] = exp(-(pz-g)^2/S)     (row stride 56 for alignment)
__global__ __launch_bounds__(256) void blur_prep(const float* __restrict__ x,
                                                 float* __restrict__ tab)
{
  int a = blockIdx.x*256 + threadIdx.x;
  if (a >= BATCH*APB) return;
  const float* row = x + (size_t)a*5;
  float p0 = row[2], p1 = row[3], p2 = row[4];
  float e[54];
  float s0 = 0.f, s1 = 0.f, s2 = 0.f;
  #pragma unroll
  for (int i = 0; i < 18; i++){
    float g = (float)i - 8.5f;
    float d0 = p0 - g, d1 = p1 - g, d2 = p2 - g;
    float v0 = __expf(d0*d0 * (-1.f/0.72f));
    float v1 = __expf(d1*d1 * (-1.f/0.72f));
    float v2 = __expf(d2*d2 * (-1.f/0.72f));
    e[i] = v0; e[18+i] = v1; e[36+i] = v2;
    s0 += v0; s1 += v1; s2 += v2;
  }
  float inv = 1.f / (s0*s1*s2 + 1e-6f);
  float* tp = tab + (size_t)a*56;
  #pragma unroll
  for (int i = 0; i < 18; i++) tp[i] = e[i]*inv;
  #pragma unroll
  for (int i = 0; i < 36; i++) tp[18+i] = e[18+i];
}

// ============ blur phase 2: accumulate fields via outer product ============
// block = (seg, ix-half). thread t<162 owns column (ix, iy), acc[18] over iz.
// ez loads have wave-uniform addresses -> scalar loads (SGPR operands to FMA).
__global__ __launch_bounds__(192) void blur_accum(const float* __restrict__ x,
                                                  const float* __restrict__ tab,
                                                  float* __restrict__ fields)
{
  int bid  = blockIdx.x;           // 0..767
  int seg  = bid >> 1;             // 0..383
  int half = bid & 1;
  int batch = seg / NA, t = seg - batch*NA;
  int tid = threadIdx.x;
  bool act = tid < 162;
  int ix = half*9 + tid/18;        // 0..17 for active lanes
  int iy = tid % 18;

  float acc[18];
  #pragma unroll
  for (int k = 0; k < 18; k++) acc[k] = 0.f;

  const float* xb = x   + (size_t)batch*APB*5;
  const float* tb = tab + (size_t)batch*APB*56;
  for (int j = 0; j < APB; j++){
    int ty = (int)xb[j*5 + 1];       // uniform -> scalar load
    if (ty != t) continue;           // uniform branch
    const float* tp = tb + j*56;
    float exv = tp[ix];              // per-lane (<=19 < 56, in-bounds even for idle lanes)
    float eyv = tp[18 + iy];
    float exy = exv * eyv;
    #pragma unroll
    for (int k = 0; k < 18; k++)
      acc[k] = fmaf(exy, tp[36 + k], acc[k]);   // tp[36+k] uniform -> s_load
  }
  if (act){
    float* fo = fields + (size_t)seg*NG + (size_t)(ix*18 + iy)*18;
    #pragma unroll
    for (int k = 0; k < 18; k++) fo[k] = acc[k];
  }
}

// ---------------- fused conv3x3x3 (SAME) + bias + maxpool 2x2x2 ----------------
template<int IC, int OC, int S, int P>
__global__ __launch_bounds__(256) void convpool_kernel(const float* __restrict__ in,
                                                       const float* __restrict__ w,
                                                       const float* __restrict__ bias,
                                                       float* __restrict__ out)
{
  int o = blockIdx.x*256 + threadIdx.x;
  constexpr int TOT = BATCH*OC*P*P*P;
  if (o >= TOT) return;
  int px = o % P; int t1 = o / P;
  int py = t1 % P; t1 /= P;
  int pz = t1 % P; t1 /= P;
  int oc = t1 % OC; int b = t1 / OC;

  float bb = bias[oc];
  float acc[8];
  #pragma unroll
  for (int i = 0; i < 8; i++) acc[i] = 0.f;

  const int z0 = 2*pz - 1, y0 = 2*py - 1, x0 = 2*px - 1;
  for (int ic = 0; ic < IC; ic++){
    const float* ip = in + (size_t)(b*IC + ic) * S*S*S;
    float r[64];
    #pragma unroll
    for (int dz = 0; dz < 4; dz++){
      int z = z0 + dz; bool zok = (unsigned)z < (unsigned)S;
      #pragma unroll
      for (int dy = 0; dy < 4; dy++){
        int y = y0 + dy; bool yok = zok && ((unsigned)y < (unsigned)S);
        #pragma unroll
        for (int dx = 0; dx < 4; dx++){
          int xx = x0 + dx; bool ok = yok && ((unsigned)xx < (unsigned)S);
          r[(dz*4+dy)*4+dx] = ok ? ip[(z*S + y)*S + xx] : 0.f;
        }
      }
    }
    const float* wp = w + (size_t)(oc*IC + ic) * 27;
    float wr[27];
    #pragma unroll
    for (int k = 0; k < 27; k++) wr[k] = wp[k];
    #pragma unroll
    for (int sz = 0; sz < 2; sz++)
      #pragma unroll
      for (int sy = 0; sy < 2; sy++)
        #pragma unroll
        for (int sx = 0; sx < 2; sx++){
          float a = acc[(sz*2+sy)*2+sx];
          #pragma unroll
          for (int dz = 0; dz < 3; dz++)
            #pragma unroll
            for (int dy = 0; dy < 3; dy++)
              #pragma unroll
              for (int dx = 0; dx < 3; dx++)
                a = fmaf(r[((sz+dz)*4 + (sy+dy))*4 + (sx+dx)], wr[(dz*3+dy)*3+dx], a);
          acc[(sz*2+sy)*2+sx] = a;
        }
  }
  float m = acc[0] + bb;
  #pragma unroll
  for (int i = 1; i < 8; i++) m = fmaxf(m, acc[i] + bb);
  out[o] = m;
}

// ---------------- BN stats, 2-stage for parallelism ----------------
template<int C, int S3, int CH>
__global__ __launch_bounds__(256) void bnstats_part(const float* __restrict__ v,
                                                    float* __restrict__ part)
{
  int c = blockIdx.x / CH, ch = blockIdx.x % CH;
  constexpr int TOT = BATCH*S3;            // elements per channel
  constexpr int PER = (TOT + CH - 1) / CH;
  int lo = ch*PER;
  int hi = lo + PER; if (hi > TOT) hi = TOT;
  float s = 0.f, s2 = 0.f;
  for (int idx = lo + threadIdx.x; idx < hi; idx += 256){
    int b = idx / S3; int sp = idx - b*S3;
    float xv = v[(size_t)(b*C + c)*S3 + sp];
    s += xv; s2 += xv*xv;
  }
  #pragma unroll
  for (int d = 32; d > 0; d >>= 1){ s += __shfl_down(s, d); s2 += __shfl_down(s2, d); }
  __shared__ float rs[4], rq[4];
  int lane = threadIdx.x & 63, wid = threadIdx.x >> 6;
  if (lane == 0){ rs[wid] = s; rq[wid] = s2; }
  __syncthreads();
  if (threadIdx.x == 0){
    part[(size_t)(c*CH + ch)*2]     = rs[0]+rs[1]+rs[2]+rs[3];
    part[(size_t)(c*CH + ch)*2 + 1] = rq[0]+rq[1]+rq[2]+rq[3];
  }
}

template<int C, int CH>
__global__ __launch_bounds__(64) void bnfinal_kernel(const float* __restrict__ part,
                                                     float* __restrict__ mean,
                                                     float* __restrict__ istd,
                                                     float n)
{
  int c = threadIdx.x;
  if (c >= C) return;
  float s = 0.f, s2 = 0.f;
  #pragma unroll
  for (int i = 0; i < CH; i++){
    s  += part[(size_t)(c*CH + i)*2];
    s2 += part[(size_t)(c*CH + i)*2 + 1];
  }
  float m = s / n;
  float var = s2 / n - m*m;
  mean[c] = m; istd[c] = rsqrtf(var + 1e-5f);
}

// ---------------- BN apply + leaky ----------------
template<int C, int S3>
__global__ __launch_bounds__(256) void bnapply_kernel(float* __restrict__ v,
                                                      const float* __restrict__ mean,
                                                      const float* __restrict__ istd,
                                                      const float* __restrict__ g,
                                                      const float* __restrict__ bb)
{
  int i = blockIdx.x*256 + threadIdx.x;
  if (i >= BATCH*C*S3) return;
  int c = (i / S3) % C;
  float xv = v[i];
  xv = (xv - mean[c]) * istd[c] * g[c] + bb[c];
  v[i] = leaky(xv);
}

// ---------------- fully connected: Y[64,O] = X[64,I] @ W[O,I]^T + b ----------------
template<int I, int O>
__global__ __launch_bounds__(256) void fc_kernel(const float* __restrict__ X,
                                                 const float* __restrict__ W,
                                                 const float* __restrict__ bias,
                                                 float* __restrict__ Y)
{
  int o = blockIdx.x*256 + threadIdx.x;
  if (o >= BATCH*O) return;
  int f = o % O; int r = o / O;
  const float4* xr = (const float4*)(X + (size_t)r*I);
  const float4* wr = (const float4*)(W + (size_t)f*I);
  float a = 0.f;
  #pragma unroll 4
  for (int i = 0; i < I/4; i++){
    float4 xv = xr[i], wv = wr[i];
    a = fmaf(xv.x, wv.x, a); a = fmaf(xv.y, wv.y, a);
    a = fmaf(xv.z, wv.z, a); a = fmaf(xv.w, wv.w, a);
  }
  Y[o] = a + bias[f];
}

// ---------------- train-mode BN over batch (=64 = one wave per feature) + leaky ----------------
template<int O>
__global__ __launch_bounds__(256) void bnrow_kernel(float* __restrict__ Y,
                                                    const float* __restrict__ g,
                                                    const float* __restrict__ bb)
{
  int gt = blockIdx.x*256 + threadIdx.x;
  int f = gt >> 6;       // one wave per feature
  int lane = gt & 63;    // lane = batch row
  if (f >= O) return;
  float xv = Y[(size_t)lane*O + f];
  float s = xv, s2 = xv*xv;
  #pragma unroll
  for (int d = 32; d > 0; d >>= 1){ s += __shfl_down(s, d); s2 += __shfl_down(s2, d); }
  s = __shfl(s, 0); s2 = __shfl(s2, 0);
  float m   = s * (1.f/64.f);
  float var = s2 * (1.f/64.f) - m*m;
  float is  = rsqrtf(var + 1e-5f);
  float y = (xv - m) * is * g[f] + bb[f];
  Y[(size_t)lane*O + f] = leaky(y);
}

// ---------------- fc2(256->100)+leaky fused with head(100->20) ----------------
__global__ __launch_bounds__(128) void mlp_tail_kernel(const float* __restrict__ H,
                                                       const float* __restrict__ w2,
                                                       const float* __restrict__ b2,
                                                       const float* __restrict__ hw,
                                                       const float* __restrict__ hb,
                                                       float* __restrict__ out)
{
  int b = blockIdx.x;
  __shared__ float y2[100];
  const float4* xr = (const float4*)(H + (size_t)b*256);
  for (int f = threadIdx.x; f < 100; f += 128){
    const float4* wr = (const float4*)(w2 + (size_t)f*256);
    float a = 0.f;
    #pragma unroll 4
    for (int i = 0; i < 64; i++){
      float4 xv = xr[i], wv = wr[i];
      a = fmaf(xv.x, wv.x, a); a = fmaf(xv.y, wv.y, a);
      a = fmaf(xv.z, wv.z, a); a = fmaf(xv.w, wv.w, a);
    }
    y2[f] = leaky(a + b2[f]);
  }
  __syncthreads();
  for (int oo = threadIdx.x; oo < 20; oo += 128){
    float a = hb[oo];
    for (int i = 0; i < 100; i++) a = fmaf(y2[i], hw[oo*100 + i], a);
    out[b*20 + oo] = a;
  }
}

extern "C" void kernel_launch(void* const* d_in, const int* in_sizes, int n_in,
                              void* d_out, int out_size, void* d_ws, size_t ws_size,
                              hipStream_t stream)
{
  const float* x   = (const float*)d_in[0];
  const float* cw0 = (const float*)d_in[2];  const float* cb0 = (const float*)d_in[3];
  const float* g0  = (const float*)d_in[4];  const float* bb0 = (const float*)d_in[5];
  const float* cw1 = (const float*)d_in[6];  const float* cb1 = (const float*)d_in[7];
  const float* g1  = (const float*)d_in[8];  const float* bb1 = (const float*)d_in[9];
  const float* cw2 = (const float*)d_in[10]; const float* cb2 = (const float*)d_in[11];
  const float* g2  = (const float*)d_in[12]; const float* bb2 = (const float*)d_in[13];
  const float* mw0 = (const float*)d_in[14]; const float* mb0 = (const float*)d_in[15];
  const float* g3  = (const float*)d_in[16]; const float* bb3 = (const float*)d_in[17];
  const float* mw1 = (const float*)d_in[18]; const float* mb1 = (const float*)d_in[19];
  const float* g4  = (const float*)d_in[20]; const float* bb4 = (const float*)d_in[21];
  const float* mw2 = (const float*)d_in[22]; const float* mb2 = (const float*)d_in[23];
  const float* hw  = (const float*)d_in[24]; const float* hb  = (const float*)d_in[25];

  float* ws     = (float*)d_ws;
  float* fields = ws;                    // 64*6*5832   = 2239488
  float* p0     = fields + 2239488;      // 746496
  float* p1     = p0 + 746496;           // 131072
  float* p2     = p1 + 131072;           // 32768 (== flattened MLP input)
  float* y0     = p2 + 32768;            // 32768
  float* y1     = y0 + 32768;            // 16384
  float* mean   = y1 + 16384;            // 64
  float* istd   = mean + 64;             // 64
  float* part   = istd + 64;             // up to 16*48*2 = 1536
  float* tab    = part + 1536;           // 32768*56 = 1835008
  float* outp   = (float*)d_out;

  blur_prep<<<128, 256, 0, stream>>>(x, tab);
  blur_accum<<<768, 192, 0, stream>>>(x, tab, fields);

  convpool_kernel<6,16,18,9><<<(746496+255)/256, 256, 0, stream>>>(fields, cw0, cb0, p0);
  bnstats_part<16,729,48><<<16*48, 256, 0, stream>>>(p0, part);
  bnfinal_kernel<16,48><<<1, 64, 0, stream>>>(part, mean, istd, 64.f*729.f);
  bnapply_kernel<16,729><<<(746496+255)/256, 256, 0, stream>>>(p0, mean, istd, g0, bb0);

  convpool_kernel<16,32,9,4><<<(131072+255)/256, 256, 0, stream>>>(p0, cw1, cb1, p1);
  bnstats_part<32,64,16><<<32*16, 256, 0, stream>>>(p1, part);
  bnfinal_kernel<32,16><<<1, 64, 0, stream>>>(part, mean, istd, 64.f*64.f);
  bnapply_kernel<32,64><<<512, 256, 0, stream>>>(p1, mean, istd, g1, bb1);

  convpool_kernel<32,64,4,2><<<128, 256, 0, stream>>>(p1, cw2, cb2, p2);
  bnstats_part<64,8,4><<<64*4, 256, 0, stream>>>(p2, part);
  bnfinal_kernel<64,4><<<1, 64, 0, stream>>>(part, mean, istd, 64.f*8.f);
  bnapply_kernel<64,8><<<128, 256, 0, stream>>>(p2, mean, istd, g2, bb2);

  fc_kernel<512,512><<<128, 256, 0, stream>>>(p2, mw0, mb0, y0);
  bnrow_kernel<512><<<128, 256, 0, stream>>>(y0, g3, bb3);
  fc_kernel<512,256><<<64, 256, 0, stream>>>(y0, mw1, mb1, y1);
  bnrow_kernel<256><<<64, 256, 0, stream>>>(y1, g4, bb4);
  mlp_tail_kernel<<<64, 128, 0, stream>>>(y1, mw2, mb2, hw, hb, outp);
}

// Round 3
// 323.642 us; speedup vs baseline: 1.8760x; 1.4298x over previous
//
#include <hip/hip_runtime.h>
#include <math.h>

#define BATCH 64
#define APB 512
#define NA 6
#define NG 5832  // 18^3

__device__ __forceinline__ float leaky(float v){ return v >= 0.f ? v : 0.01f*v; }

// ============ blur phase 1: per-atom separable 1-D Gaussian tables ============
__global__ __launch_bounds__(256) void blur_prep(const float* __restrict__ x,
                                                 float* __restrict__ tab)
{
  int a = blockIdx.x*256 + threadIdx.x;
  if (a >= BATCH*APB) return;
  const float* row = x + (size_t)a*5;
  float p0 = row[2], p1 = row[3], p2 = row[4];
  float e[54];
  float s0 = 0.f, s1 = 0.f, s2 = 0.f;
  #pragma unroll
  for (int i = 0; i < 18; i++){
    float g = (float)i - 8.5f;
    float d0 = p0 - g, d1 = p1 - g, d2 = p2 - g;
    float v0 = __expf(d0*d0 * (-1.f/0.72f));
    float v1 = __expf(d1*d1 * (-1.f/0.72f));
    float v2 = __expf(d2*d2 * (-1.f/0.72f));
    e[i] = v0; e[18+i] = v1; e[36+i] = v2;
    s0 += v0; s1 += v1; s2 += v2;
  }
  float inv = 1.f / (s0*s1*s2 + 1e-6f);
  float* tp = tab + (size_t)a*56;
  #pragma unroll
  for (int i = 0; i < 18; i++) tp[i] = e[i]*inv;
  #pragma unroll
  for (int i = 0; i < 36; i++) tp[18+i] = e[18+i];
}

// ============ blur phase 2: outer-product accumulation ============
__global__ __launch_bounds__(192) void blur_accum(const float* __restrict__ x,
                                                  const float* __restrict__ tab,
                                                  float* __restrict__ fields)
{
  int bid  = blockIdx.x;           // 0..767
  int seg  = bid >> 1;
  int half = bid & 1;
  int batch = seg / NA, t = seg - batch*NA;
  int tid = threadIdx.x;
  bool act = tid < 162;
  int ix = half*9 + tid/18;
  int iy = tid % 18;

  float acc[18];
  #pragma unroll
  for (int k = 0; k < 18; k++) acc[k] = 0.f;

  const float* xb = x   + (size_t)batch*APB*5;
  const float* tb = tab + (size_t)batch*APB*56;
  for (int j = 0; j < APB; j++){
    int ty = (int)xb[j*5 + 1];
    if (ty != t) continue;
    const float* tp = tb + j*56;
    float exv = tp[ix];
    float eyv = tp[18 + iy];
    float exy = exv * eyv;
    #pragma unroll
    for (int k = 0; k < 18; k++)
      acc[k] = fmaf(exy, tp[36 + k], acc[k]);
  }
  if (act){
    float* fo = fields + (size_t)seg*NG + (size_t)(ix*18 + iy)*18;
    #pragma unroll
    for (int k = 0; k < 18; k++) fo[k] = acc[k];
  }
}

// ============ conv0: 6->16, 18^3 -> pool 9^3, LDS-staged ============
__global__ __launch_bounds__(192) void conv0_kernel(const float* __restrict__ in,
                                                    const float* __restrict__ w,
                                                    const float* __restrict__ bias,
                                                    float* __restrict__ out)
{
  __shared__ float in_s[6*4*324];   // [ic][zl][y*18+x]
  __shared__ float w_s[2592];
  int bid = blockIdx.x;
  int b = bid / 9, pz = bid - b*9;
  int tid = threadIdx.x;

  for (int idx = tid; idx < 6*4*324; idx += 192){
    int ic = idx / 1296; int r = idx - ic*1296;
    int zl = r / 324;    int sp = r - zl*324;
    int gz = 2*pz - 1 + zl;
    float v = 0.f;
    if ((unsigned)gz < 18u) v = in[(size_t)(b*6+ic)*5832 + gz*324 + sp];
    in_s[idx] = v;
  }
  for (int idx = tid; idx < 2592; idx += 192) w_s[idx] = w[idx];
  __syncthreads();

  if (tid < 144){
    int oc = tid / 9, py = tid - oc*9;
    float acc[2][2][18];
    #pragma unroll
    for (int i=0;i<2;i++)
      #pragma unroll
      for (int j=0;j<2;j++)
        #pragma unroll
        for (int k=0;k<18;k++) acc[i][j][k]=0.f;

    for (int ic=0; ic<6; ic++){
      float wr[27];
      #pragma unroll
      for (int k=0;k<27;k++) wr[k] = w_s[(oc*6+ic)*27 + k];
      #pragma unroll
      for (int zl=0; zl<4; zl++){
        #pragma unroll
        for (int yl=0; yl<4; yl++){
          int gy = 2*py - 1 + yl;
          if ((unsigned)gy < 18u){
            const float* rp = &in_s[((ic*4+zl)*18 + gy)*18];
            float row[18];
            #pragma unroll
            for (int xx=0; xx<18; xx++) row[xx] = rp[xx];
            #pragma unroll
            for (int czl=0; czl<2; czl++){
              if (zl-czl < 0 || zl-czl > 2) continue;
              #pragma unroll
              for (int cyl=0; cyl<2; cyl++){
                if (yl-cyl < 0 || yl-cyl > 2) continue;
                const int wb = (zl-czl)*9 + (yl-cyl)*3;
                #pragma unroll
                for (int cx=0; cx<18; cx++){
                  float a = acc[czl][cyl][cx];
                  #pragma unroll
                  for (int dx=0; dx<3; dx++){
                    int sx = cx - 1 + dx;
                    if (sx >= 0 && sx < 18) a = fmaf(row[sx], wr[wb+dx], a);
                  }
                  acc[czl][cyl][cx] = a;
                }
              }
            }
          }
        }
      }
    }
    float bb = bias[oc];
    float* op = out + (((size_t)(b*16 + oc)*9 + pz)*9 + py)*9;
    #pragma unroll
    for (int px=0; px<9; px++){
      float m = acc[0][0][2*px];
      m = fmaxf(m, acc[0][0][2*px+1]);
      m = fmaxf(m, acc[0][1][2*px]);  m = fmaxf(m, acc[0][1][2*px+1]);
      m = fmaxf(m, acc[1][0][2*px]);  m = fmaxf(m, acc[1][0][2*px+1]);
      m = fmaxf(m, acc[1][1][2*px]);  m = fmaxf(m, acc[1][1][2*px+1]);
      op[px] = m + bb;
    }
  }
}

// ============ conv1: 16->32, 9^3 -> pool 4^3, BN0 fused into staging ============
__global__ __launch_bounds__(256) void conv1_kernel(const float* __restrict__ in,
                                                    const float* __restrict__ w,
                                                    const float* __restrict__ bias,
                                                    const float* __restrict__ sc,
                                                    const float* __restrict__ sh,
                                                    float* __restrict__ out)
{
  __shared__ float in_s[16*4*81];
  __shared__ float w_s[13824 + 32];
  int bid = blockIdx.x;
  int b = bid >> 2, pz = bid & 3;
  int tid = threadIdx.x;

  for (int idx = tid; idx < 16*4*81; idx += 256){
    int ic = idx / 324; int r = idx - ic*324;
    int zl = r / 81;    int sp = r - zl*81;
    int gz = 2*pz - 1 + zl;
    float v = 0.f;
    if ((unsigned)gz < 9u){
      float raw = in[(size_t)(b*16+ic)*729 + gz*81 + sp];
      v = leaky(fmaf(raw, sc[ic], sh[ic]));
    }
    in_s[idx] = v;
  }
  for (int idx = tid; idx < 13824; idx += 256){
    int ocw = idx / 432;
    w_s[idx + ocw] = w[idx];
  }
  __syncthreads();

  int oc = tid >> 3, py = (tid >> 1) & 3, xh = tid & 1;
  float acc[2][2][4];
  #pragma unroll
  for (int i=0;i<2;i++)
    #pragma unroll
    for (int j=0;j<2;j++)
      #pragma unroll
      for (int k=0;k<4;k++) acc[i][j][k]=0.f;

  for (int ic=0; ic<16; ic++){
    float wr[27];
    #pragma unroll
    for (int k=0;k<27;k++) wr[k] = w_s[oc*433 + ic*27 + k];
    #pragma unroll
    for (int zl=0; zl<4; zl++){
      #pragma unroll
      for (int yl=0; yl<4; yl++){
        int gy = 2*py - 1 + yl;
        float row[6];
        if ((unsigned)gy < 9u){
          #pragma unroll
          for (int i=0;i<6;i++){
            int sx = 4*xh - 1 + i;
            row[i] = ((unsigned)sx < 9u) ? in_s[((ic*4+zl)*9+gy)*9 + sx] : 0.f;
          }
        } else {
          #pragma unroll
          for (int i=0;i<6;i++) row[i]=0.f;
        }
        #pragma unroll
        for (int czl=0;czl<2;czl++){
          if (zl-czl<0||zl-czl>2) continue;
          #pragma unroll
          for (int cyl=0;cyl<2;cyl++){
            if (yl-cyl<0||yl-cyl>2) continue;
            const int wb = (zl-czl)*9+(yl-cyl)*3;
            #pragma unroll
            for (int cx=0;cx<4;cx++){
              float a = acc[czl][cyl][cx];
              #pragma unroll
              for (int dx=0;dx<3;dx++) a = fmaf(row[cx+dx], wr[wb+dx], a);
              acc[czl][cyl][cx]=a;
            }
          }
        }
      }
    }
  }
  float bb = bias[oc];
  float* op = out + (((size_t)(b*32+oc)*4 + pz)*4 + py)*4 + xh*2;
  #pragma unroll
  for (int p=0;p<2;p++){
    float m = acc[0][0][2*p];  m=fmaxf(m,acc[0][0][2*p+1]);
    m=fmaxf(m,acc[0][1][2*p]); m=fmaxf(m,acc[0][1][2*p+1]);
    m=fmaxf(m,acc[1][0][2*p]); m=fmaxf(m,acc[1][0][2*p+1]);
    m=fmaxf(m,acc[1][1][2*p]); m=fmaxf(m,acc[1][1][2*p+1]);
    op[p] = m + bb;
  }
}

// ============ conv2: 32->64, 4^3 -> pool 2^3, BN1 fused, chunked weights ============
__global__ __launch_bounds__(256) void conv2_kernel(const float* __restrict__ in,
                                                    const float* __restrict__ w,
                                                    const float* __restrict__ bias,
                                                    const float* __restrict__ sc,
                                                    const float* __restrict__ sh,
                                                    float* __restrict__ out)
{
  __shared__ float in_s[32*4*16];
  __shared__ float w_s[13824 + 64];
  int bid = blockIdx.x;
  int b = bid >> 1, pz = bid & 1;
  int tid = threadIdx.x;

  for (int idx = tid; idx < 2048; idx += 256){
    int ic = idx >> 6; int r = idx & 63;
    int zl = r >> 4;   int sp = r & 15;
    int gz = 2*pz - 1 + zl;
    float v = 0.f;
    if ((unsigned)gz < 4u){
      float raw = in[(size_t)(b*32+ic)*64 + gz*16 + sp];
      v = leaky(fmaf(raw, sc[ic], sh[ic]));
    }
    in_s[idx] = v;
  }

  int oc = tid >> 2, py = (tid >> 1) & 1, px = tid & 1;
  float acc[2][2][2];
  #pragma unroll
  for (int i=0;i<2;i++)
    #pragma unroll
    for (int j=0;j<2;j++)
      #pragma unroll
      for (int k=0;k<2;k++) acc[i][j][k]=0.f;

  for (int cc = 0; cc < 4; cc++){
    __syncthreads();
    for (int idx = tid; idx < 13824; idx += 256){
      int ocw = idx / 216; int inner = idx - ocw*216;
      w_s[ocw*217 + inner] = w[(size_t)ocw*864 + cc*216 + inner];
    }
    __syncthreads();
    for (int icl = 0; icl < 8; icl++){
      int ic = cc*8 + icl;
      float wr[27];
      #pragma unroll
      for (int k=0;k<27;k++) wr[k] = w_s[oc*217 + icl*27 + k];
      #pragma unroll
      for (int zl=0; zl<4; zl++){
        #pragma unroll
        for (int yl=0; yl<4; yl++){
          int gy = 2*py - 1 + yl;
          float row[4];
          if ((unsigned)gy < 4u){
            #pragma unroll
            for (int i=0;i<4;i++){
              int sx = 2*px - 1 + i;
              row[i] = ((unsigned)sx < 4u) ? in_s[(ic*4+zl)*16 + gy*4 + sx] : 0.f;
            }
          } else {
            #pragma unroll
            for (int i=0;i<4;i++) row[i]=0.f;
          }
          #pragma unroll
          for (int czl=0;czl<2;czl++){
            if (zl-czl<0||zl-czl>2) continue;
            #pragma unroll
            for (int cyl=0;cyl<2;cyl++){
              if (yl-cyl<0||yl-cyl>2) continue;
              const int wb=(zl-czl)*9+(yl-cyl)*3;
              #pragma unroll
              for (int cx=0;cx<2;cx++){
                float a = acc[czl][cyl][cx];
                #pragma unroll
                for (int dx=0;dx<3;dx++) a=fmaf(row[cx+dx],wr[wb+dx],a);
                acc[czl][cyl][cx]=a;
              }
            }
          }
        }
      }
    }
  }
  float bb = bias[oc];
  float m = acc[0][0][0];
  m=fmaxf(m,acc[0][0][1]); m=fmaxf(m,acc[0][1][0]); m=fmaxf(m,acc[0][1][1]);
  m=fmaxf(m,acc[1][0][0]); m=fmaxf(m,acc[1][0][1]); m=fmaxf(m,acc[1][1][0]); m=fmaxf(m,acc[1][1][1]);
  out[(size_t)(b*64+oc)*8 + pz*4 + py*2 + px] = m + bb;
}

// ---------------- BN stats, 2-stage ----------------
template<int C, int S3, int CH>
__global__ __launch_bounds__(256) void bnstats_part(const float* __restrict__ v,
                                                    float* __restrict__ part)
{
  int c = blockIdx.x / CH, ch = blockIdx.x % CH;
  constexpr int TOT = BATCH*S3;
  constexpr int PER = (TOT + CH - 1) / CH;
  int lo = ch*PER;
  int hi = lo + PER; if (hi > TOT) hi = TOT;
  float s = 0.f, s2 = 0.f;
  for (int idx = lo + threadIdx.x; idx < hi; idx += 256){
    int b = idx / S3; int sp = idx - b*S3;
    float xv = v[(size_t)(b*C + c)*S3 + sp];
    s += xv; s2 += xv*xv;
  }
  #pragma unroll
  for (int d = 32; d > 0; d >>= 1){ s += __shfl_down(s, d); s2 += __shfl_down(s2, d); }
  __shared__ float rs[4], rq[4];
  int lane = threadIdx.x & 63, wid = threadIdx.x >> 6;
  if (lane == 0){ rs[wid] = s; rq[wid] = s2; }
  __syncthreads();
  if (threadIdx.x == 0){
    part[(size_t)(c*CH + ch)*2]     = rs[0]+rs[1]+rs[2]+rs[3];
    part[(size_t)(c*CH + ch)*2 + 1] = rq[0]+rq[1]+rq[2]+rq[3];
  }
}

// final: emit per-channel scale = istd*g, shift = b - mean*scale
template<int C, int CH>
__global__ __launch_bounds__(64) void bnfinal_kernel(const float* __restrict__ part,
                                                     float* __restrict__ scale,
                                                     float* __restrict__ shift,
                                                     const float* __restrict__ g,
                                                     const float* __restrict__ bb,
                                                     float n)
{
  int c = threadIdx.x;
  if (c >= C) return;
  float s = 0.f, s2 = 0.f;
  #pragma unroll
  for (int i = 0; i < CH; i++){
    s  += part[(size_t)(c*CH + i)*2];
    s2 += part[(size_t)(c*CH + i)*2 + 1];
  }
  float m = s / n;
  float var = s2 / n - m*m;
  float is = rsqrtf(var + 1e-5f);
  float scv = is * g[c];
  scale[c] = scv;
  shift[c] = bb[c] - m * scv;
}

// ---------------- fc0 with BN2+leaky fused on the X load ----------------
__global__ __launch_bounds__(256) void fc0_bn_kernel(const float* __restrict__ X,
                                                     const float* __restrict__ W,
                                                     const float* __restrict__ bias,
                                                     const float* __restrict__ sc,
                                                     const float* __restrict__ sh,
                                                     float* __restrict__ Y)
{
  int o = blockIdx.x*256 + threadIdx.x;   // 64*512
  if (o >= BATCH*512) return;
  int f = o & 511; int r = o >> 9;
  const float* xr = X + (size_t)r*512;
  const float* wr = W + (size_t)f*512;
  float a = 0.f;
  for (int c = 0; c < 64; c++){
    float s = sc[c], h = sh[c];
    #pragma unroll
    for (int j = 0; j < 8; j++){
      float xv = leaky(fmaf(xr[c*8+j], s, h));
      a = fmaf(xv, wr[c*8+j], a);
    }
  }
  Y[o] = a + bias[f];
}

// ---------------- plain fc ----------------
template<int I, int O>
__global__ __launch_bounds__(256) void fc_kernel(const float* __restrict__ X,
                                                 const float* __restrict__ W,
                                                 const float* __restrict__ bias,
                                                 float* __restrict__ Y)
{
  int o = blockIdx.x*256 + threadIdx.x;
  if (o >= BATCH*O) return;
  int f = o % O; int r = o / O;
  const float4* xr = (const float4*)(X + (size_t)r*I);
  const float4* wr = (const float4*)(W + (size_t)f*I);
  float a = 0.f;
  #pragma unroll 4
  for (int i = 0; i < I/4; i++){
    float4 xv = xr[i], wv = wr[i];
    a = fmaf(xv.x, wv.x, a); a = fmaf(xv.y, wv.y, a);
    a = fmaf(xv.z, wv.z, a); a = fmaf(xv.w, wv.w, a);
  }
  Y[o] = a + bias[f];
}

// ---------------- MLP BN over batch (one wave per feature) + leaky ----------------
template<int O>
__global__ __launch_bounds__(256) void bnrow_kernel(float* __restrict__ Y,
                                                    const float* __restrict__ g,
                                                    const float* __restrict__ bb)
{
  int gt = blockIdx.x*256 + threadIdx.x;
  int f = gt >> 6;
  int lane = gt & 63;
  if (f >= O) return;
  float xv = Y[(size_t)lane*O + f];
  float s = xv, s2 = xv*xv;
  #pragma unroll
  for (int d = 32; d > 0; d >>= 1){ s += __shfl_down(s, d); s2 += __shfl_down(s2, d); }
  s = __shfl(s, 0); s2 = __shfl(s2, 0);
  float m   = s * (1.f/64.f);
  float var = s2 * (1.f/64.f) - m*m;
  float is  = rsqrtf(var + 1e-5f);
  float y = (xv - m) * is * g[f] + bb[f];
  Y[(size_t)lane*O + f] = leaky(y);
}

// ---------------- fc2(256->100)+leaky fused with head(100->20) ----------------
__global__ __launch_bounds__(128) void mlp_tail_kernel(const float* __restrict__ H,
                                                       const float* __restrict__ w2,
                                                       const float* __restrict__ b2,
                                                       const float* __restrict__ hw,
                                                       const float* __restrict__ hb,
                                                       float* __restrict__ out)
{
  int b = blockIdx.x;
  __shared__ float y2[100];
  const float4* xr = (const float4*)(H + (size_t)b*256);
  for (int f = threadIdx.x; f < 100; f += 128){
    const float4* wr = (const float4*)(w2 + (size_t)f*256);
    float a = 0.f;
    #pragma unroll 4
    for (int i = 0; i < 64; i++){
      float4 xv = xr[i], wv = wr[i];
      a = fmaf(xv.x, wv.x, a); a = fmaf(xv.y, wv.y, a);
      a = fmaf(xv.z, wv.z, a); a = fmaf(xv.w, wv.w, a);
    }
    y2[f] = leaky(a + b2[f]);
  }
  __syncthreads();
  for (int oo = threadIdx.x; oo < 20; oo += 128){
    float a = hb[oo];
    for (int i = 0; i < 100; i++) a = fmaf(y2[i], hw[oo*100 + i], a);
    out[b*20 + oo] = a;
  }
}

extern "C" void kernel_launch(void* const* d_in, const int* in_sizes, int n_in,
                              void* d_out, int out_size, void* d_ws, size_t ws_size,
                              hipStream_t stream)
{
  const float* x   = (const float*)d_in[0];
  const float* cw0 = (const float*)d_in[2];  const float* cb0 = (const float*)d_in[3];
  const float* g0  = (const float*)d_in[4];  const float* bb0 = (const float*)d_in[5];
  const float* cw1 = (const float*)d_in[6];  const float* cb1 = (const float*)d_in[7];
  const float* g1  = (const float*)d_in[8];  const float* bb1 = (const float*)d_in[9];
  const float* cw2 = (const float*)d_in[10]; const float* cb2 = (const float*)d_in[11];
  const float* g2  = (const float*)d_in[12]; const float* bb2 = (const float*)d_in[13];
  const float* mw0 = (const float*)d_in[14]; const float* mb0 = (const float*)d_in[15];
  const float* g3  = (const float*)d_in[16]; const float* bb3 = (const float*)d_in[17];
  const float* mw1 = (const float*)d_in[18]; const float* mb1 = (const float*)d_in[19];
  const float* g4  = (const float*)d_in[20]; const float* bb4 = (const float*)d_in[21];
  const float* mw2 = (const float*)d_in[22]; const float* mb2 = (const float*)d_in[23];
  const float* hw  = (const float*)d_in[24]; const float* hb  = (const float*)d_in[25];

  float* ws     = (float*)d_ws;
  float* fields = ws;                    // 2239488
  float* p0     = fields + 2239488;      // 746496
  float* p1     = p0 + 746496;           // 131072
  float* p2     = p1 + 131072;           // 32768
  float* y0     = p2 + 32768;            // 32768
  float* y1     = y0 + 32768;            // 16384
  float* part   = y1 + 16384;            // 1536
  float* sc0    = part + 1536;           // 16
  float* sh0    = sc0 + 16;              // 16
  float* sc1    = sh0 + 16;              // 32
  float* sh1    = sc1 + 32;              // 32
  float* sc2    = sh1 + 32;              // 64
  float* sh2    = sc2 + 64;              // 64
  float* tab    = sh2 + 64;              // 32768*56
  float* outp   = (float*)d_out;

  blur_prep<<<128, 256, 0, stream>>>(x, tab);
  blur_accum<<<768, 192, 0, stream>>>(x, tab, fields);

  conv0_kernel<<<576, 192, 0, stream>>>(fields, cw0, cb0, p0);
  bnstats_part<16,729,48><<<768, 256, 0, stream>>>(p0, part);
  bnfinal_kernel<16,48><<<1, 64, 0, stream>>>(part, sc0, sh0, g0, bb0, 64.f*729.f);

  conv1_kernel<<<256, 256, 0, stream>>>(p0, cw1, cb1, sc0, sh0, p1);
  bnstats_part<32,64,16><<<512, 256, 0, stream>>>(p1, part);
  bnfinal_kernel<32,16><<<1, 64, 0, stream>>>(part, sc1, sh1, g1, bb1, 64.f*64.f);

  conv2_kernel<<<128, 256, 0, stream>>>(p1, cw2, cb2, sc1, sh1, p2);
  bnstats_part<64,8,4><<<256, 256, 0, stream>>>(p2, part);
  bnfinal_kernel<64,4><<<1, 64, 0, stream>>>(part, sc2, sh2, g2, bb2, 64.f*8.f);

  fc0_bn_kernel<<<128, 256, 0, stream>>>(p2, mw0, mb0, sc2, sh2, y0);
  bnrow_kernel<512><<<128, 256, 0, stream>>>(y0, g3, bb3);
  fc_kernel<512,256><<<64, 256, 0, stream>>>(y0, mw1, mb1, y1);
  bnrow_kernel<256><<<64, 256, 0, stream>>>(y1, g4, bb4);
  mlp_tail_kernel<<<64, 128, 0, stream>>>(y1, mw2, mb2, hw, hb, outp);
}

// Round 4
// 289.013 us; speedup vs baseline: 2.1008x; 1.1198x over previous
//
#include <hip/hip_runtime.h>
#include <math.h>

#define BATCH 64
#define APB 512
#define NA 6
#define NG 5832  // 18^3

__device__ __forceinline__ float leaky(float v){ return v >= 0.f ? v : 0.01f*v; }

// ============ atom sort: deterministic counting sort by (batch, type) ============
__global__ __launch_bounds__(64) void atom_sort(const float* __restrict__ x,
                                                int* __restrict__ dst,
                                                int* __restrict__ seg_start,
                                                int* __restrict__ seg_count)
{
  int batch = blockIdx.x;
  int lane  = threadIdx.x;
  int tyc[8];
  int cnt[NA];
  #pragma unroll
  for (int t = 0; t < NA; t++) cnt[t] = 0;
  #pragma unroll
  for (int c = 0; c < 8; c++){
    int a = batch*APB + c*64 + lane;
    int ty = (int)x[(size_t)a*5 + 1];
    tyc[c] = ty;
    #pragma unroll
    for (int t = 0; t < NA; t++){
      unsigned long long m = __ballot(ty == t);
      cnt[t] += __popcll(m);
    }
  }
  int pre[NA+1];
  pre[0] = 0;
  #pragma unroll
  for (int t = 0; t < NA; t++) pre[t+1] = pre[t] + cnt[t];
  if (lane < NA){
    seg_start[batch*NA + lane] = batch*APB + pre[lane];
    seg_count[batch*NA + lane] = cnt[lane];
  }
  int run[NA];
  #pragma unroll
  for (int t = 0; t < NA; t++) run[t] = pre[t];
  unsigned long long below = (lane == 0) ? 0ull : ((~0ull) >> (64 - lane));
  #pragma unroll
  for (int c = 0; c < 8; c++){
    int a = batch*APB + c*64 + lane;
    int ty = tyc[c];
    int rank = 0;
    #pragma unroll
    for (int t = 0; t < NA; t++){
      unsigned long long m = __ballot(ty == t);
      if (ty == t) rank = run[t] + __popcll(m & below);
      run[t] += __popcll(m);
    }
    dst[a] = batch*APB + rank;
  }
}

// ============ blur phase 1: per-atom separable 1-D tables (sorted rows) ============
// row stride 64: x at [0,18) (pads 18,19 zeroed), y at [20,38), z at [40,58)
__global__ __launch_bounds__(256) void blur_prep(const float* __restrict__ x,
                                                 const int* __restrict__ dst,
                                                 float* __restrict__ tab)
{
  int a = blockIdx.x*256 + threadIdx.x;
  if (a >= BATCH*APB) return;
  const float* row = x + (size_t)a*5;
  float p0 = row[2], p1 = row[3], p2 = row[4];
  float e[54];
  float s0 = 0.f, s1 = 0.f, s2 = 0.f;
  #pragma unroll
  for (int i = 0; i < 18; i++){
    float g = (float)i - 8.5f;
    float d0 = p0 - g, d1 = p1 - g, d2 = p2 - g;
    float v0 = __expf(d0*d0 * (-1.f/0.72f));
    float v1 = __expf(d1*d1 * (-1.f/0.72f));
    float v2 = __expf(d2*d2 * (-1.f/0.72f));
    e[i] = v0; e[18+i] = v1; e[36+i] = v2;
    s0 += v0; s1 += v1; s2 += v2;
  }
  float inv = 1.f / (s0*s1*s2 + 1e-6f);
  float* tp = tab + (size_t)dst[a]*64;
  #pragma unroll
  for (int i = 0; i < 18; i++) tp[i] = e[i]*inv;
  tp[18] = 0.f; tp[19] = 0.f;
  #pragma unroll
  for (int i = 0; i < 18; i++) tp[20+i] = e[18+i];
  #pragma unroll
  for (int i = 0; i < 18; i++) tp[40+i] = e[36+i];
}

// ============ blur phase 2: branch-free streaming outer-product ============
__global__ __launch_bounds__(192) void blur_accum(const float* __restrict__ tab,
                                                  const int* __restrict__ seg_start,
                                                  const int* __restrict__ seg_count,
                                                  float* __restrict__ fields)
{
  int bid  = blockIdx.x;           // 0..767
  int seg  = bid >> 1;
  int half = bid & 1;
  int tid = threadIdx.x;
  bool act = tid < 162;
  int ix = half*9 + tid/18;        // <=17 active; 18/19 for idle lanes (zeroed pad)
  int iy = tid % 18;

  float acc[18];
  #pragma unroll
  for (int k = 0; k < 18; k++) acc[k] = 0.f;

  int start = seg_start[seg], count = seg_count[seg];
  const float* tb = tab + (size_t)start*64;

  int j = 0;
  for (; j + 3 < count; j += 4){
    const float* t0 = tb + (size_t)(j+0)*64;
    const float* t1 = tb + (size_t)(j+1)*64;
    const float* t2 = tb + (size_t)(j+2)*64;
    const float* t3 = tb + (size_t)(j+3)*64;
    float e0 = t0[ix]*t0[20+iy];
    float e1 = t1[ix]*t1[20+iy];
    float e2 = t2[ix]*t2[20+iy];
    float e3 = t3[ix]*t3[20+iy];
    #pragma unroll
    for (int k = 0; k < 18; k++){
      float a = acc[k];
      a = fmaf(e0, t0[40+k], a);
      a = fmaf(e1, t1[40+k], a);
      a = fmaf(e2, t2[40+k], a);
      a = fmaf(e3, t3[40+k], a);
      acc[k] = a;
    }
  }
  for (; j < count; j++){
    const float* t0 = tb + (size_t)j*64;
    float e0 = t0[ix]*t0[20+iy];
    #pragma unroll
    for (int k = 0; k < 18; k++)
      acc[k] = fmaf(e0, t0[40+k], acc[k]);
  }
  if (act){
    float* fo = fields + (size_t)seg*NG + (size_t)(ix*18 + iy)*18;
    #pragma unroll
    for (int k = 0; k < 18; k++) fo[k] = acc[k];
  }
}

// ============ conv0: 6->16, 18^3 -> pool 9^3, LDS-staged ============
__global__ __launch_bounds__(192) void conv0_kernel(const float* __restrict__ in,
                                                    const float* __restrict__ w,
                                                    const float* __restrict__ bias,
                                                    float* __restrict__ out)
{
  __shared__ float in_s[6*4*324];   // [ic][zl][y*18+x]
  __shared__ float w_s[2592];
  int bid = blockIdx.x;
  int b = bid / 9, pz = bid - b*9;
  int tid = threadIdx.x;

  for (int idx = tid; idx < 6*4*324; idx += 192){
    int ic = idx / 1296; int r = idx - ic*1296;
    int zl = r / 324;    int sp = r - zl*324;
    int gz = 2*pz - 1 + zl;
    float v = 0.f;
    if ((unsigned)gz < 18u) v = in[(size_t)(b*6+ic)*5832 + gz*324 + sp];
    in_s[idx] = v;
  }
  for (int idx = tid; idx < 2592; idx += 192) w_s[idx] = w[idx];
  __syncthreads();

  if (tid < 144){
    int oc = tid / 9, py = tid - oc*9;
    float acc[2][2][18];
    #pragma unroll
    for (int i=0;i<2;i++)
      #pragma unroll
      for (int j=0;j<2;j++)
        #pragma unroll
        for (int k=0;k<18;k++) acc[i][j][k]=0.f;

    for (int ic=0; ic<6; ic++){
      float wr[27];
      #pragma unroll
      for (int k=0;k<27;k++) wr[k] = w_s[(oc*6+ic)*27 + k];
      #pragma unroll
      for (int zl=0; zl<4; zl++){
        #pragma unroll
        for (int yl=0; yl<4; yl++){
          int gy = 2*py - 1 + yl;
          if ((unsigned)gy < 18u){
            const float* rp = &in_s[((ic*4+zl)*18 + gy)*18];
            float row[18];
            #pragma unroll
            for (int xx=0; xx<18; xx++) row[xx] = rp[xx];
            #pragma unroll
            for (int czl=0; czl<2; czl++){
              if (zl-czl < 0 || zl-czl > 2) continue;
              #pragma unroll
              for (int cyl=0; cyl<2; cyl++){
                if (yl-cyl < 0 || yl-cyl > 2) continue;
                const int wb = (zl-czl)*9 + (yl-cyl)*3;
                #pragma unroll
                for (int cx=0; cx<18; cx++){
                  float a = acc[czl][cyl][cx];
                  #pragma unroll
                  for (int dx=0; dx<3; dx++){
                    int sx = cx - 1 + dx;
                    if (sx >= 0 && sx < 18) a = fmaf(row[sx], wr[wb+dx], a);
                  }
                  acc[czl][cyl][cx] = a;
                }
              }
            }
          }
        }
      }
    }
    float bb = bias[oc];
    float* op = out + (((size_t)(b*16 + oc)*9 + pz)*9 + py)*9;
    #pragma unroll
    for (int px=0; px<9; px++){
      float m = acc[0][0][2*px];
      m = fmaxf(m, acc[0][0][2*px+1]);
      m = fmaxf(m, acc[0][1][2*px]);  m = fmaxf(m, acc[0][1][2*px+1]);
      m = fmaxf(m, acc[1][0][2*px]);  m = fmaxf(m, acc[1][0][2*px+1]);
      m = fmaxf(m, acc[1][1][2*px]);  m = fmaxf(m, acc[1][1][2*px+1]);
      op[px] = m + bb;
    }
  }
}

// ============ conv1: 16->32, 9^3 -> pool 4^3, BN0 fused into staging ============
__global__ __launch_bounds__(256) void conv1_kernel(const float* __restrict__ in,
                                                    const float* __restrict__ w,
                                                    const float* __restrict__ bias,
                                                    const float* __restrict__ sc,
                                                    const float* __restrict__ sh,
                                                    float* __restrict__ out)
{
  __shared__ float in_s[16*4*81];
  __shared__ float w_s[13824 + 32];
  int bid = blockIdx.x;
  int b = bid >> 2, pz = bid & 3;
  int tid = threadIdx.x;

  for (int idx = tid; idx < 16*4*81; idx += 256){
    int ic = idx / 324; int r = idx - ic*324;
    int zl = r / 81;    int sp = r - zl*81;
    int gz = 2*pz - 1 + zl;
    float v = 0.f;
    if ((unsigned)gz < 9u){
      float raw = in[(size_t)(b*16+ic)*729 + gz*81 + sp];
      v = leaky(fmaf(raw, sc[ic], sh[ic]));
    }
    in_s[idx] = v;
  }
  for (int idx = tid; idx < 13824; idx += 256){
    int ocw = idx / 432;
    w_s[idx + ocw] = w[idx];
  }
  __syncthreads();

  int oc = tid >> 3, py = (tid >> 1) & 3, xh = tid & 1;
  float acc[2][2][4];
  #pragma unroll
  for (int i=0;i<2;i++)
    #pragma unroll
    for (int j=0;j<2;j++)
      #pragma unroll
      for (int k=0;k<4;k++) acc[i][j][k]=0.f;

  for (int ic=0; ic<16; ic++){
    float wr[27];
    #pragma unroll
    for (int k=0;k<27;k++) wr[k] = w_s[oc*433 + ic*27 + k];
    #pragma unroll
    for (int zl=0; zl<4; zl++){
      #pragma unroll
      for (int yl=0; yl<4; yl++){
        int gy = 2*py - 1 + yl;
        float row[6];
        if ((unsigned)gy < 9u){
          #pragma unroll
          for (int i=0;i<6;i++){
            int sx = 4*xh - 1 + i;
            row[i] = ((unsigned)sx < 9u) ? in_s[((ic*4+zl)*9+gy)*9 + sx] : 0.f;
          }
        } else {
          #pragma unroll
          for (int i=0;i<6;i++) row[i]=0.f;
        }
        #pragma unroll
        for (int czl=0;czl<2;czl++){
          if (zl-czl<0||zl-czl>2) continue;
          #pragma unroll
          for (int cyl=0;cyl<2;cyl++){
            if (yl-cyl<0||yl-cyl>2) continue;
            const int wb = (zl-czl)*9+(yl-cyl)*3;
            #pragma unroll
            for (int cx=0;cx<4;cx++){
              float a = acc[czl][cyl][cx];
              #pragma unroll
              for (int dx=0;dx<3;dx++) a = fmaf(row[cx+dx], wr[wb+dx], a);
              acc[czl][cyl][cx]=a;
            }
          }
        }
      }
    }
  }
  float bb = bias[oc];
  float* op = out + (((size_t)(b*32+oc)*4 + pz)*4 + py)*4 + xh*2;
  #pragma unroll
  for (int p=0;p<2;p++){
    float m = acc[0][0][2*p];  m=fmaxf(m,acc[0][0][2*p+1]);
    m=fmaxf(m,acc[0][1][2*p]); m=fmaxf(m,acc[0][1][2*p+1]);
    m=fmaxf(m,acc[1][0][2*p]); m=fmaxf(m,acc[1][0][2*p+1]);
    m=fmaxf(m,acc[1][1][2*p]); m=fmaxf(m,acc[1][1][2*p+1]);
    op[p] = m + bb;
  }
}

// ============ conv2: 32->64, 4^3 -> pool 2^3, BN1 fused, TRANSPOSED store ============
__global__ __launch_bounds__(256) void conv2_kernel(const float* __restrict__ in,
                                                    const float* __restrict__ w,
                                                    const float* __restrict__ bias,
                                                    const float* __restrict__ sc,
                                                    const float* __restrict__ sh,
                                                    float* __restrict__ out)  // [64ch*8sp][64b]
{
  __shared__ float in_s[32*4*16];
  __shared__ float w_s[13824 + 64];
  int bid = blockIdx.x;
  int b = bid >> 1, pz = bid & 1;
  int tid = threadIdx.x;

  for (int idx = tid; idx < 2048; idx += 256){
    int ic = idx >> 6; int r = idx & 63;
    int zl = r >> 4;   int sp = r & 15;
    int gz = 2*pz - 1 + zl;
    float v = 0.f;
    if ((unsigned)gz < 4u){
      float raw = in[(size_t)(b*32+ic)*64 + gz*16 + sp];
      v = leaky(fmaf(raw, sc[ic], sh[ic]));
    }
    in_s[idx] = v;
  }

  int oc = tid >> 2, py = (tid >> 1) & 1, px = tid & 1;
  float acc[2][2][2];
  #pragma unroll
  for (int i=0;i<2;i++)
    #pragma unroll
    for (int j=0;j<2;j++)
      #pragma unroll
      for (int k=0;k<2;k++) acc[i][j][k]=0.f;

  for (int cc = 0; cc < 4; cc++){
    __syncthreads();
    for (int idx = tid; idx < 13824; idx += 256){
      int ocw = idx / 216; int inner = idx - ocw*216;
      w_s[ocw*217 + inner] = w[(size_t)ocw*864 + cc*216 + inner];
    }
    __syncthreads();
    for (int icl = 0; icl < 8; icl++){
      int ic = cc*8 + icl;
      float wr[27];
      #pragma unroll
      for (int k=0;k<27;k++) wr[k] = w_s[oc*217 + icl*27 + k];
      #pragma unroll
      for (int zl=0; zl<4; zl++){
        #pragma unroll
        for (int yl=0; yl<4; yl++){
          int gy = 2*py - 1 + yl;
          float row[4];
          if ((unsigned)gy < 4u){
            #pragma unroll
            for (int i=0;i<4;i++){
              int sx = 2*px - 1 + i;
              row[i] = ((unsigned)sx < 4u) ? in_s[(ic*4+zl)*16 + gy*4 + sx] : 0.f;
            }
          } else {
            #pragma unroll
            for (int i=0;i<4;i++) row[i]=0.f;
          }
          #pragma unroll
          for (int czl=0;czl<2;czl++){
            if (zl-czl<0||zl-czl>2) continue;
            #pragma unroll
            for (int cyl=0;cyl<2;cyl++){
              if (yl-cyl<0||yl-cyl>2) continue;
              const int wb=(zl-czl)*9+(yl-cyl)*3;
              #pragma unroll
              for (int cx=0;cx<2;cx++){
                float a = acc[czl][cyl][cx];
                #pragma unroll
                for (int dx=0;dx<3;dx++) a=fmaf(row[cx+dx],wr[wb+dx],a);
                acc[czl][cyl][cx]=a;
              }
            }
          }
        }
      }
    }
  }
  float bb = bias[oc];
  float m = acc[0][0][0];
  m=fmaxf(m,acc[0][0][1]); m=fmaxf(m,acc[0][1][0]); m=fmaxf(m,acc[0][1][1]);
  m=fmaxf(m,acc[1][0][0]); m=fmaxf(m,acc[1][0][1]); m=fmaxf(m,acc[1][1][0]); m=fmaxf(m,acc[1][1][1]);
  out[(size_t)(oc*8 + pz*4 + py*2 + px)*64 + b] = m + bb;
}

// ---------------- BN stats (layers 0,1), 2-stage ----------------
template<int C, int S3, int CH>
__global__ __launch_bounds__(256) void bnstats_part(const float* __restrict__ v,
                                                    float* __restrict__ part)
{
  int c = blockIdx.x / CH, ch = blockIdx.x % CH;
  constexpr int TOT = BATCH*S3;
  constexpr int PER = (TOT + CH - 1) / CH;
  int lo = ch*PER;
  int hi = lo + PER; if (hi > TOT) hi = TOT;
  float s = 0.f, s2 = 0.f;
  for (int idx = lo + threadIdx.x; idx < hi; idx += 256){
    int b = idx / S3; int sp = idx - b*S3;
    float xv = v[(size_t)(b*C + c)*S3 + sp];
    s += xv; s2 += xv*xv;
  }
  #pragma unroll
  for (int d = 32; d > 0; d >>= 1){ s += __shfl_down(s, d); s2 += __shfl_down(s2, d); }
  __shared__ float rs[4], rq[4];
  int lane = threadIdx.x & 63, wid = threadIdx.x >> 6;
  if (lane == 0){ rs[wid] = s; rq[wid] = s2; }
  __syncthreads();
  if (threadIdx.x == 0){
    part[(size_t)(c*CH + ch)*2]     = rs[0]+rs[1]+rs[2]+rs[3];
    part[(size_t)(c*CH + ch)*2 + 1] = rq[0]+rq[1]+rq[2]+rq[3];
  }
}

template<int C, int CH>
__global__ __launch_bounds__(64) void bnfinal_kernel(const float* __restrict__ part,
                                                     float* __restrict__ scale,
                                                     float* __restrict__ shift,
                                                     const float* __restrict__ g,
                                                     const float* __restrict__ bb,
                                                     float n)
{
  int c = threadIdx.x;
  if (c >= C) return;
  float s = 0.f, s2 = 0.f;
  #pragma unroll
  for (int i = 0; i < CH; i++){
    s  += part[(size_t)(c*CH + i)*2];
    s2 += part[(size_t)(c*CH + i)*2 + 1];
  }
  float m = s / n;
  float var = s2 / n - m*m;
  float is = rsqrtf(var + 1e-5f);
  float scv = is * g[c];
  scale[c] = scv;
  shift[c] = bb[c] - m * scv;
}

// ---------------- BN2 stats on transposed p2t: one wave per channel ----------------
__global__ __launch_bounds__(256) void bn2t_kernel(const float* __restrict__ p2t,
                                                   const float* __restrict__ g,
                                                   const float* __restrict__ bb,
                                                   float* __restrict__ scale,
                                                   float* __restrict__ shift)
{
  int gt = blockIdx.x*256 + threadIdx.x;
  int c = gt >> 6, lane = gt & 63;
  if (c >= 64) return;
  const float* p = p2t + (size_t)c*512;
  float s = 0.f, s2 = 0.f;
  #pragma unroll
  for (int i = 0; i < 8; i++){ float v = p[i*64 + lane]; s += v; s2 += v*v; }
  #pragma unroll
  for (int d = 32; d > 0; d >>= 1){ s += __shfl_down(s, d); s2 += __shfl_down(s2, d); }
  if (lane == 0){
    float m = s * (1.f/512.f);
    float var = s2 * (1.f/512.f) - m*m;
    float scv = rsqrtf(var + 1e-5f) * g[c];
    scale[c] = scv;
    shift[c] = bb[c] - m*scv;
  }
}

// ---------------- fc0 (512->512) + BN2-on-load + batch-BN3 + leaky, wave/feature ----------------
__global__ __launch_bounds__(256) void fc0bn_kernel(const float* __restrict__ p2t,
                                                    const float* __restrict__ W,
                                                    const float* __restrict__ bias,
                                                    const float* __restrict__ sc,
                                                    const float* __restrict__ sh,
                                                    const float* __restrict__ g,
                                                    const float* __restrict__ bb,
                                                    float* __restrict__ y0t)
{
  int gt = blockIdx.x*256 + threadIdx.x;
  int f = gt >> 6, r = gt & 63;
  const float* wr = W + (size_t)f*512;
  float a = 0.f;
  for (int c = 0; c < 64; c++){
    float s = sc[c], h = sh[c];
    #pragma unroll
    for (int jj = 0; jj < 8; jj++){
      int i = c*8 + jj;
      float xv = leaky(fmaf(p2t[(size_t)i*64 + r], s, h));
      a = fmaf(xv, wr[i], a);
    }
  }
  a += bias[f];
  float s1 = a, s2 = a*a;
  #pragma unroll
  for (int d = 32; d > 0; d >>= 1){ s1 += __shfl_down(s1, d); s2 += __shfl_down(s2, d); }
  s1 = __shfl(s1, 0); s2 = __shfl(s2, 0);
  float m = s1 * (1.f/64.f);
  float var = s2 * (1.f/64.f) - m*m;
  float is = rsqrtf(var + 1e-5f);
  y0t[(size_t)f*64 + r] = leaky((a - m) * is * g[f] + bb[f]);
}

// ---------------- fc1 (512->256) + batch-BN4 + leaky, wave/feature ----------------
__global__ __launch_bounds__(256) void fc1bn_kernel(const float* __restrict__ y0t,
                                                    const float* __restrict__ W,
                                                    const float* __restrict__ bias,
                                                    const float* __restrict__ g,
                                                    const float* __restrict__ bb,
                                                    float* __restrict__ y1t)
{
  int gt = blockIdx.x*256 + threadIdx.x;
  int f = gt >> 6, r = gt & 63;
  const float* wr = W + (size_t)f*512;
  float a = 0.f;
  #pragma unroll 4
  for (int i = 0; i < 512; i++)
    a = fmaf(y0t[(size_t)i*64 + r], wr[i], a);
  a += bias[f];
  float s1 = a, s2 = a*a;
  #pragma unroll
  for (int d = 32; d > 0; d >>= 1){ s1 += __shfl_down(s1, d); s2 += __shfl_down(s2, d); }
  s1 = __shfl(s1, 0); s2 = __shfl(s2, 0);
  float m = s1 * (1.f/64.f);
  float var = s2 * (1.f/64.f) - m*m;
  float is = rsqrtf(var + 1e-5f);
  y1t[(size_t)f*64 + r] = leaky((a - m) * is * g[f] + bb[f]);
}

// ---------------- fc2 (256->100) + leaky, wave/feature ----------------
__global__ __launch_bounds__(256) void fc2_kernel(const float* __restrict__ y1t,
                                                  const float* __restrict__ W,
                                                  const float* __restrict__ bias,
                                                  float* __restrict__ y2t)
{
  int gt = blockIdx.x*256 + threadIdx.x;
  int f = gt >> 6, r = gt & 63;
  if (f >= 100) return;
  const float* wr = W + (size_t)f*256;
  float a = 0.f;
  #pragma unroll 4
  for (int i = 0; i < 256; i++)
    a = fmaf(y1t[(size_t)i*64 + r], wr[i], a);
  y2t[(size_t)f*64 + r] = leaky(a + bias[f]);
}

// ---------------- head (100->20), wave/output ----------------
__global__ __launch_bounds__(256) void head_kernel(const float* __restrict__ y2t,
                                                   const float* __restrict__ W,
                                                   const float* __restrict__ bias,
                                                   float* __restrict__ out)
{
  int gt = blockIdx.x*256 + threadIdx.x;
  int oo = gt >> 6, r = gt & 63;
  if (oo >= 20) return;
  const float* wr = W + (size_t)oo*100;
  float a = 0.f;
  #pragma unroll 4
  for (int i = 0; i < 100; i++)
    a = fmaf(y2t[(size_t)i*64 + r], wr[i], a);
  out[(size_t)r*20 + oo] = a + bias[oo];
}

extern "C" void kernel_launch(void* const* d_in, const int* in_sizes, int n_in,
                              void* d_out, int out_size, void* d_ws, size_t ws_size,
                              hipStream_t stream)
{
  const float* x   = (const float*)d_in[0];
  const float* cw0 = (const float*)d_in[2];  const float* cb0 = (const float*)d_in[3];
  const float* g0  = (const float*)d_in[4];  const float* bb0 = (const float*)d_in[5];
  const float* cw1 = (const float*)d_in[6];  const float* cb1 = (const float*)d_in[7];
  const float* g1  = (const float*)d_in[8];  const float* bb1 = (const float*)d_in[9];
  const float* cw2 = (const float*)d_in[10]; const float* cb2 = (const float*)d_in[11];
  const float* g2  = (const float*)d_in[12]; const float* bb2 = (const float*)d_in[13];
  const float* mw0 = (const float*)d_in[14]; const float* mb0 = (const float*)d_in[15];
  const float* g3  = (const float*)d_in[16]; const float* bb3 = (const float*)d_in[17];
  const float* mw1 = (const float*)d_in[18]; const float* mb1 = (const float*)d_in[19];
  const float* g4  = (const float*)d_in[20]; const float* bb4 = (const float*)d_in[21];
  const float* mw2 = (const float*)d_in[22]; const float* mb2 = (const float*)d_in[23];
  const float* hw  = (const float*)d_in[24]; const float* hb  = (const float*)d_in[25];

  float* ws     = (float*)d_ws;
  float* fields = ws;                    // 2239488
  float* p0     = fields + 2239488;      // 746496
  float* p1     = p0 + 746496;           // 131072
  float* p2t    = p1 + 131072;           // 32768   [512][64]
  float* y0t    = p2t + 32768;           // 32768   [512][64]
  float* y1t    = y0t + 32768;           // 16384   [256][64]
  float* y2t    = y1t + 16384;           // 6400    [100][64]
  float* part   = y2t + 6400;            // 1536
  float* sc0    = part + 1536;           // 16
  float* sh0    = sc0 + 16;
  float* sc1    = sh0 + 16;              // 32
  float* sh1    = sc1 + 32;
  float* sc2    = sh1 + 32;              // 64
  float* sh2    = sc2 + 64;
  float* tab    = sh2 + 64;              // 32768*64 = 2097152
  int*   dst    = (int*)(tab + 2097152); // 32768
  int*   sstart = dst + 32768;           // 384
  int*   scount = sstart + 384;          // 384
  float* outp   = (float*)d_out;

  atom_sort<<<64, 64, 0, stream>>>(x, dst, sstart, scount);
  blur_prep<<<128, 256, 0, stream>>>(x, dst, tab);
  blur_accum<<<768, 192, 0, stream>>>(tab, sstart, scount, fields);

  conv0_kernel<<<576, 192, 0, stream>>>(fields, cw0, cb0, p0);
  bnstats_part<16,729,48><<<768, 256, 0, stream>>>(p0, part);
  bnfinal_kernel<16,48><<<1, 64, 0, stream>>>(part, sc0, sh0, g0, bb0, 64.f*729.f);

  conv1_kernel<<<256, 256, 0, stream>>>(p0, cw1, cb1, sc0, sh0, p1);
  bnstats_part<32,64,16><<<512, 256, 0, stream>>>(p1, part);
  bnfinal_kernel<32,16><<<1, 64, 0, stream>>>(part, sc1, sh1, g1, bb1, 64.f*64.f);

  conv2_kernel<<<128, 256, 0, stream>>>(p1, cw2, cb2, sc1, sh1, p2t);
  bn2t_kernel<<<16, 256, 0, stream>>>(p2t, g2, bb2, sc2, sh2);

  fc0bn_kernel<<<128, 256, 0, stream>>>(p2t, mw0, mb0, sc2, sh2, g3, bb3, y0t);
  fc1bn_kernel<<<64, 256, 0, stream>>>(y0t, mw1, mb1, g4, bb4, y1t);
  fc2_kernel<<<25, 256, 0, stream>>>(y1t, mw2, mb2, y2t);
  head_kernel<<<5, 256, 0, stream>>>(y2t, hw, hb, outp);
}